// Round 13
// baseline (92.307 us; speedup 1.0000x reference)
//
#include <hip/hip_runtime.h>

// HyperPatchNoPadding:
//   x: [8, 64, 256, 256] f32, s: [8, 4096, 16, 16] f32, out: [8, 64, 256, 256] f32
//   Per patch (b,pi,pj): Y[o][p*16+q] = sum_c W[o][c] * X[c][p*16+q]
// Round 13: single kernel = R7's proven gemm body (block = (b,pi,ph,pjp),
// 8 p-rows x 2 patches, wide-VMEM x/out staging through LDS) with the W path
// gathered in-kernel (R12's proven s->fragment mapping) instead of a separate
// pack kernel + workspace. Deletes ~10us serial pack + 32MB ws round-trip.
#define NB 8

typedef __bf16 bf16x8 __attribute__((ext_vector_type(8)));
typedef float  f32x4  __attribute__((ext_vector_type(4)));

__global__ __launch_bounds__(256, 2) void fused_gemm(
    const float* __restrict__ x,
    const float* __restrict__ s,
    float* __restrict__ out)
{
    // LDS: [0,8K) W-frags patch0, [8K,16K) W-frags patch1,
    //      [16K,48K) x-tile (R7 layout) reused as f32 epilogue staging.
    __shared__ char smem[49152];
    char* smemX = smem + 16384;
    float* ef   = (float*)(smem + 16384);

    const int bid = blockIdx.x;            // 0..2047
    const int b   = bid & 7;               // XCD bits -> b (R7 decode, proven)
    const int pi  = (bid >> 3) & 15;
    const int ph  = (bid >> 7) & 1;        // p half
    const int pjp = (bid >> 8) & 7;        // pj pair
    const int t   = threadIdx.x;           // 0..255
    const int lane = t & 63;
    const int wv   = t >> 6;               // 0..3
    const int pat  = wv & 1;               // patch within pair
    const int wrow = wv >> 1;              // p quad
    const int q    = lane & 15;
    const int hi   = lane >> 4;
    const int w0   = pjp * 32;             // float offset of pair in W-dim
    const int row0 = pi * 16 + ph * 8;     // global h-row base

    // ---- issue all global loads: 16 x-loads (16B) + 16 s-loads (8B) ----
    const int swq = lane & 7;              // w-quad (w = swq*4+i)
    const int sco = lane >> 3;             // c-octet (c = sco*8+cc)
    const float* xrowbase = x + (size_t)(b * 64 + sco * 8) * 65536
                              + (size_t)row0 * 256 + w0 + swq * 4;
    f32x4 xv[16];
    #pragma unroll
    for (int pp = 0; pp < 2; ++pp)
        #pragma unroll
        for (int cc = 0; cc < 8; ++cc)
            xv[pp * 8 + cc] = *(const f32x4*)(xrowbase + (size_t)cc * 65536
                                              + (size_t)(wv * 2 + pp) * 256);

    // s element (o,c) for patches (pi, pjp*2 / +1): float2 at row r=o*64+c
    const float2* sp2 = (const float2*)(s + (size_t)b * 1048576 + pi * 16 + pjp * 2);
    float2 sv[16];
    #pragma unroll
    for (int k = 0; k < 16; ++k)
        sv[k] = sp2[(size_t)(t + k * 256) * 128];

    // ---- W fragments -> LDS (R12-proven mapping) ----
    #pragma unroll
    for (int k = 0; k < 16; ++k) {
        const int r = t + k * 256;         // 0..4095 = o*64+c
        const int o = r >> 6, c = r & 63;
        const int ent = ((o >> 4) * 2 + (c >> 5)) * 64 + ((c >> 3) & 3) * 16 + (o & 15);
        const int byt = ent * 16 + (c & 7) * 2;
        *(__bf16*)(smem + byt)        = (__bf16)sv[k].x;   // patch 0
        *(__bf16*)(smem + 8192 + byt) = (__bf16)sv[k].y;   // patch 1
    }

    // ---- x tile -> LDS (R7-proven layout) ----
    #pragma unroll
    for (int pp = 0; pp < 2; ++pp) {
        const int p = wv * 2 + pp;         // 0..7
        #pragma unroll
        for (int i = 0; i < 4; ++i) {
            const int w = swq * 4 + i;
            bf16x8 e;
            #pragma unroll
            for (int cc = 0; cc < 8; ++cc)
                e[cc] = (__bf16)xv[pp * 8 + cc][i];
            *(bf16x8*)(smemX + p * 4096 + w * 128
                       + ((sco * 16) ^ ((w & 7) << 4) ^ ((p & 7) << 4))) = e;
        }
    }
    __syncthreads();

    // ---- A fragments from LDS W region ----
    bf16x8 a[4][2];
    #pragma unroll
    for (int mt = 0; mt < 4; ++mt)
        #pragma unroll
        for (int kk = 0; kk < 2; ++kk)
            a[mt][kk] = *(const bf16x8*)(smem + pat * 8192
                          + ((mt * 2 + kk) * 64 + lane) * 16);

    // ---- B fragments: one ds_read_b128 each (R7-proven) ----
    bf16x8 bfrag[4][2];
    #pragma unroll
    for (int nt = 0; nt < 4; ++nt) {
        const int p = wrow * 4 + nt;       // 0..7
        const int w = pat * 16 + q;
        #pragma unroll
        for (int kk = 0; kk < 2; ++kk) {
            const int co = kk * 4 + hi;
            bfrag[nt][kk] = *(const bf16x8*)(smemX + p * 4096 + w * 128
                            + ((co * 16) ^ ((w & 7) << 4) ^ ((p & 7) << 4)));
        }
    }
    __syncthreads();                       // x-LDS reusable for out-stage

    // ---- MFMA + out staging in two o-halves (R7-proven) ----
    const int u2t = t >> 3;                // 0..31
    const int wq2 = t & 7;
    #pragma unroll
    for (int h2 = 0; h2 < 2; ++h2) {
        f32x4 acc[2][4];
        #pragma unroll
        for (int m2 = 0; m2 < 2; ++m2)
            #pragma unroll
            for (int nt = 0; nt < 4; ++nt)
                acc[m2][nt] = (f32x4){0.f, 0.f, 0.f, 0.f};

        #pragma unroll
        for (int m2 = 0; m2 < 2; ++m2) {
            const int mt = h2 * 2 + m2;
            #pragma unroll
            for (int nt = 0; nt < 4; ++nt) {
                acc[m2][nt] = __builtin_amdgcn_mfma_f32_16x16x32_bf16(
                    a[mt][0], bfrag[nt][0], acc[m2][nt], 0, 0, 0);
                acc[m2][nt] = __builtin_amdgcn_mfma_f32_16x16x32_bf16(
                    a[mt][1], bfrag[nt][1], acc[m2][nt], 0, 0, 0);
            }
        }

        // acc -> LDS f32 (R7 swizzle)
        #pragma unroll
        for (int m2 = 0; m2 < 2; ++m2)
            #pragma unroll
            for (int nt = 0; nt < 4; ++nt) {
                const int p = wrow * 4 + nt;
                #pragma unroll
                for (int r = 0; r < 4; ++r) {
                    const int o2 = m2 * 16 + hi * 4 + r;
                    const int w  = pat * 16 + q;
                    ef[(o2 * 8 + p) * 32 + (w ^ ((o2 & 7) << 2))] = acc[m2][nt][r];
                }
            }
        __syncthreads();

        // wide f32x4 stores: 8 passes x 32 full 128-B lines (R7)
        #pragma unroll
        for (int ps = 0; ps < 8; ++ps) {
            const int r2 = ps * 32 + u2t;  // 0..255
            const int o2 = r2 >> 3;
            const int p  = r2 & 7;
            f32x4 vv = *(const f32x4*)&ef[(o2 * 8 + p) * 32
                                          + ((wq2 * 4) ^ ((o2 & 7) << 2))];
            *(f32x4*)(out + (size_t)(b * 64 + h2 * 32 + o2) * 65536
                          + (size_t)(row0 + p) * 256 + w0 + wq2 * 4) = vv;
        }
        if (h2 == 0) __syncthreads();
    }
}

extern "C" void kernel_launch(void* const* d_in, const int* in_sizes, int n_in,
                              void* d_out, int out_size, void* d_ws, size_t ws_size,
                              hipStream_t stream)
{
    (void)in_sizes; (void)n_in; (void)out_size; (void)d_ws; (void)ws_size;
    const float* x = (const float*)d_in[0];
    const float* s = (const float*)d_in[1];
    float* out = (float*)d_out;

    fused_gemm<<<dim3(2048), dim3(256), 0, stream>>>(x, s, out);
}

// Round 14
// 72.428 us; speedup vs baseline: 1.2745x; 1.2745x over previous
//
#include <hip/hip_runtime.h>

// HyperPatchNoPadding:
//   x: [8, 64, 256, 256] f32, s: [8, 4096, 16, 16] f32, out: [8, 64, 256, 256] f32
//   Per patch (b,pi,pj): Y[o][p*16+q] = sum_c W[o][c] * X[c][p*16+q]
// Round 14: restore Round 7 verbatim (best measured: 73.3 us total).
// Two-kernel: K1 packs W (coalesced s read -> bf16 MFMA fragments in ws),
// K2 GEMM with wide-VMEM x/out staging through 32 KiB LDS, 4 blocks/CU.
#define NB 8
#define FH 16
#define FW 16

typedef __bf16 bf16x8 __attribute__((ext_vector_type(8)));
typedef float  f32x4  __attribute__((ext_vector_type(4)));

#define WS_BYTES ((size_t)NB * 256 * 512 * 16)  // 16 MiB

// ---------------------------------------------------------------------------
// K1: pack/transpose s -> ws (proven).  ws[patch][g]: g=(mt*2+kk)*64+gl holds
// W[mt*16+(gl&15)][kk*32+(gl>>4)*8+j]
// ---------------------------------------------------------------------------
__global__ __launch_bounds__(256) void pack_w_kernel(
    const float* __restrict__ s, bf16x8* __restrict__ ws)
{
    __shared__ float lds[16 * 513];
    const int bid = blockIdx.x;              // 0..1023
    const int b   = bid & 7;                 // XCD bits -> b
    const int pi  = (bid >> 3) & 15;
    const int mt  = (bid >> 7) & 3;
    const int kk  = (bid >> 9) & 1;
    const int tid = threadIdx.x;

    #pragma unroll
    for (int pass = 0; pass < 8; ++pass) {
        const int idx   = pass * 256 + tid;
        const int u     = idx >> 2;
        const int pj4   = idx & 3;
        const int row16 = u >> 5;
        const int cc    = u & 31;
        const size_t row = (size_t)b * 4096 + mt * 1024 + row16 * 64 + kk * 32 + cc;
        const float4 v = *reinterpret_cast<const float4*>(
            s + row * 256 + pi * 16 + pj4 * 4);
        lds[(pj4 * 4 + 0) * 513 + cc * 16 + row16] = v.x;
        lds[(pj4 * 4 + 1) * 513 + cc * 16 + row16] = v.y;
        lds[(pj4 * 4 + 2) * 513 + cc * 16 + row16] = v.z;
        lds[(pj4 * 4 + 3) * 513 + cc * 16 + row16] = v.w;
    }
    __syncthreads();

    const int gl     = tid & 63;
    const int row16  = gl & 15;
    const int lanehi = gl >> 4;
    #pragma unroll
    for (int pjblk = 0; pjblk < 4; ++pjblk) {
        const int pj = pjblk * 4 + (tid >> 6);
        bf16x8 e;
        #pragma unroll
        for (int j = 0; j < 8; ++j)
            e[j] = (__bf16)lds[pj * 513 + (lanehi * 8 + j) * 16 + row16];
        ws[((size_t)(b * 256 + pi * 16 + pj)) * 512 + (mt * 2 + kk) * 64 + gl] = e;
    }
}

// ---------------------------------------------------------------------------
// K2: GEMM. Block = (b, pi, ph, pjp): 8 p-rows x 2 patches. 256 thr / 4 waves,
// 32 KiB LDS dual-purpose.
// x-LDS: byte(p,w,c) = p*4096 + w*128 + ((c*2) ^ ((w&7)<<4) ^ ((p&7)<<4)), p<8
// ---------------------------------------------------------------------------
__global__ __launch_bounds__(256, 4) void gemm_kernel(
    const float* __restrict__ x,
    const bf16x8* __restrict__ ws,
    float* __restrict__ out)
{
    __shared__ char smem[32768];
    float* smemf = (float*)smem;

    const int bid = blockIdx.x;            // 0..2047
    const int b   = bid & 7;               // XCD bits -> b
    const int pi  = (bid >> 3) & 15;
    const int ph  = (bid >> 7) & 1;        // p half (rows pi*16+ph*8 ..+7)
    const int pjp = (bid >> 8) & 7;        // pj pair
    const int t   = threadIdx.x;           // 0..255
    const int lane = t & 63;
    const int wv   = t >> 6;               // 0..3
    const int pat  = wv & 1;               // patch within pair
    const int wrow = wv >> 1;              // p quad (p = wrow*4+nt)
    const int q    = lane & 15;
    const int hi   = lane >> 4;
    const int w0   = pjp * 32;             // float offset of pair in W-dim
    const int row0 = pi * 16 + ph * 8;     // global h-row base

    // ---- A fragments from ws (coalesced 16 B/lane) ----
    const bf16x8* wbase = ws + ((size_t)(b * 256 + pi * 16 + pjp * 2 + pat)) * 512;
    bf16x8 a[4][2];
    #pragma unroll
    for (int mt = 0; mt < 4; ++mt)
        #pragma unroll
        for (int kk = 0; kk < 2; ++kk)
            a[mt][kk] = wbase[(mt * 2 + kk) * 64 + lane];

    // ---- stage x -> LDS: lane owns (p = wv*2+pp, w-quad = lane&7, c-octet = lane>>3)
    {
        const int swq = lane & 7;          // w-quad (w = swq*4+i)
        const int sco = lane >> 3;         // c-octet (c = sco*8+cc)
        #pragma unroll
        for (int pp = 0; pp < 2; ++pp) {
            const int p = wv * 2 + pp;     // 0..7
            const float* xp = x + ((size_t)(b * 64 + sco * 8)) * 65536
                                + (size_t)(row0 + p) * 256 + w0 + swq * 4;
            f32x4 v[8];
            #pragma unroll
            for (int cc = 0; cc < 8; ++cc)
                v[cc] = *(const f32x4*)(xp + (size_t)cc * 65536);  // full 128-B lines
            #pragma unroll
            for (int i = 0; i < 4; ++i) {
                const int w = swq * 4 + i;
                bf16x8 e;
                #pragma unroll
                for (int cc = 0; cc < 8; ++cc)
                    e[cc] = (__bf16)v[cc][i];
                *(bf16x8*)(smem + p * 4096 + w * 128
                           + ((sco * 16) ^ ((w & 7) << 4) ^ ((p & 7) << 4))) = e;
            }
        }
    }
    __syncthreads();

    // ---- B fragments: one ds_read_b128 each ----
    bf16x8 bfrag[4][2];
    #pragma unroll
    for (int nt = 0; nt < 4; ++nt) {
        const int p = wrow * 4 + nt;       // 0..7
        const int w = pat * 16 + q;
        #pragma unroll
        for (int kk = 0; kk < 2; ++kk) {
            const int co = kk * 4 + hi;
            bfrag[nt][kk] = *(const bf16x8*)(smem + p * 4096 + w * 128
                            + ((co * 16) ^ ((w & 7) << 4) ^ ((p & 7) << 4)));
        }
    }
    __syncthreads();                       // x-LDS reusable for out-stage

    // ---- MFMA + out staging in two o-halves (o = h*32 + o2) ----
    const int u2t = t >> 3;                // 0..31
    const int wq2 = t & 7;
    #pragma unroll
    for (int h = 0; h < 2; ++h) {
        f32x4 acc[2][4];
        #pragma unroll
        for (int m2 = 0; m2 < 2; ++m2)
            #pragma unroll
            for (int nt = 0; nt < 4; ++nt)
                acc[m2][nt] = (f32x4){0.f, 0.f, 0.f, 0.f};

        #pragma unroll
        for (int m2 = 0; m2 < 2; ++m2) {
            const int mt = h * 2 + m2;
            #pragma unroll
            for (int nt = 0; nt < 4; ++nt) {
                acc[m2][nt] = __builtin_amdgcn_mfma_f32_16x16x32_bf16(
                    a[mt][0], bfrag[nt][0], acc[m2][nt], 0, 0, 0);
                acc[m2][nt] = __builtin_amdgcn_mfma_f32_16x16x32_bf16(
                    a[mt][1], bfrag[nt][1], acc[m2][nt], 0, 0, 0);
            }
        }

        // acc -> LDS: f32 idx (o2*8 + p)*32 + (w ^ ((o2&7)<<2)), 32 KiB
        #pragma unroll
        for (int m2 = 0; m2 < 2; ++m2)
            #pragma unroll
            for (int nt = 0; nt < 4; ++nt) {
                const int p = wrow * 4 + nt;
                #pragma unroll
                for (int r = 0; r < 4; ++r) {
                    const int o2 = m2 * 16 + hi * 4 + r;
                    const int w  = pat * 16 + q;
                    smemf[(o2 * 8 + p) * 32 + (w ^ ((o2 & 7) << 2))] = acc[m2][nt][r];
                }
            }
        __syncthreads();

        // wide f32x4 stores: 8 passes x 32 lines (full 128-B lines)
        #pragma unroll
        for (int ps = 0; ps < 8; ++ps) {
            const int r2 = ps * 32 + u2t;  // 0..255
            const int o2 = r2 >> 3;
            const int p  = r2 & 7;
            f32x4 vv = *(const f32x4*)&smemf[(o2 * 8 + p) * 32
                                             + ((wq2 * 4) ^ ((o2 & 7) << 2))];
            *(f32x4*)(out + ((size_t)(b * 64 + h * 32 + o2)) * 65536
                          + (size_t)(row0 + p) * 256 + w0 + wq2 * 4) = vv;
        }
        __syncthreads();
    }
}

// ---------------------------------------------------------------------------
// Fallback (round-2 single kernel, proven) if ws is too small.
// ---------------------------------------------------------------------------
__global__ __launch_bounds__(512) void hyperpatch_fallback(
    const float* __restrict__ x,
    const float* __restrict__ s,
    float* __restrict__ out)
{
    __shared__ bf16x8 afrag[2][512];
    const int bid = blockIdx.x;
    const int b   = bid >> 7;
    const int pi  = (bid >> 3) & 15;
    const int pj0 = (bid & 7) * 2;
    const int t   = threadIdx.x;
    const int lane = t & 63;
    const int wv   = t >> 6;

    {
        const int g  = t;
        const int mt = g >> 7;
        const int kk = (g >> 6) & 1;
        const int gl = g & 63;
        const int o  = mt * 16 + (gl & 15);
        const int c0 = kk * 32 + (gl >> 4) * 8;
        const float2* sb2 = reinterpret_cast<const float2*>(
            s + ((size_t)b * 4096) * 256 + pi * 16 + pj0);
        bf16x8 ta, tb;
        #pragma unroll
        for (int j = 0; j < 8; ++j) {
            float2 v = sb2[(size_t)(o * 64 + c0 + j) * 128];
            ta[j] = (__bf16)v.x;
            tb[j] = (__bf16)v.y;
        }
        afrag[0][g] = ta;
        afrag[1][g] = tb;
    }

    const int pat  = wv >> 2;
    const int wrow = wv & 3;
    const int q  = lane & 15;
    const int cb = (lane >> 4) * 8;
    const float* xbase = x + (((size_t)b * 64) * 256 + pi * 16) * 256
                           + (pj0 + pat) * 16 + q;
    bf16x8 bfrag[4][2];
    #pragma unroll
    for (int nt = 0; nt < 4; ++nt) {
        const int p = wrow * 4 + nt;
        #pragma unroll
        for (int kk = 0; kk < 2; ++kk) {
            const int c = kk * 32 + cb;
            bf16x8 tv;
            #pragma unroll
            for (int j = 0; j < 8; ++j) {
                float v = xbase[(size_t)(c + j) * 65536 + (size_t)p * 256];
                tv[j] = (__bf16)v;
            }
            bfrag[nt][kk] = tv;
        }
    }

    __syncthreads();

    bf16x8 a[4][2];
    #pragma unroll
    for (int mt = 0; mt < 4; ++mt)
        #pragma unroll
        for (int kk = 0; kk < 2; ++kk)
            a[mt][kk] = afrag[pat][(mt * 2 + kk) * 64 + lane];

    f32x4 acc[4][4];
    #pragma unroll
    for (int mt = 0; mt < 4; ++mt)
        #pragma unroll
        for (int nt = 0; nt < 4; ++nt)
            acc[mt][nt] = (f32x4){0.f, 0.f, 0.f, 0.f};

    #pragma unroll
    for (int mt = 0; mt < 4; ++mt) {
        #pragma unroll
        for (int nt = 0; nt < 4; ++nt) {
            acc[mt][nt] = __builtin_amdgcn_mfma_f32_16x16x32_bf16(
                a[mt][0], bfrag[nt][0], acc[mt][nt], 0, 0, 0);
            acc[mt][nt] = __builtin_amdgcn_mfma_f32_16x16x32_bf16(
                a[mt][1], bfrag[nt][1], acc[mt][nt], 0, 0, 0);
        }
    }

    const int ro = (lane >> 4) * 4;
    float* obase = out + (((size_t)b * 64) * 256 + pi * 16) * 256
                       + (pj0 + pat) * 16 + q;
    #pragma unroll
    for (int mt = 0; mt < 4; ++mt) {
        #pragma unroll
        for (int nt = 0; nt < 4; ++nt) {
            const int p = wrow * 4 + nt;
            #pragma unroll
            for (int r = 0; r < 4; ++r) {
                const int o = mt * 16 + ro + r;
                obase[(size_t)o * 65536 + (size_t)p * 256] = acc[mt][nt][r];
            }
        }
    }
}

extern "C" void kernel_launch(void* const* d_in, const int* in_sizes, int n_in,
                              void* d_out, int out_size, void* d_ws, size_t ws_size,
                              hipStream_t stream)
{
    (void)in_sizes; (void)n_in; (void)out_size;
    const float* x = (const float*)d_in[0];
    const float* s = (const float*)d_in[1];
    float* out = (float*)d_out;

    if (ws_size >= WS_BYTES && d_ws != nullptr) {
        bf16x8* ws = (bf16x8*)d_ws;
        pack_w_kernel<<<dim3(1024), dim3(256), 0, stream>>>(s, ws);
        gemm_kernel<<<dim3(2048), dim3(256), 0, stream>>>(x, ws, out);
    } else {
        hyperpatch_fallback<<<dim3(NB * FH * (FW / 2)), dim3(512), 0, stream>>>(x, s, out);
    }
}